// Round 2
// baseline (185.636 us; speedup 1.0000x reference)
//
#include <hip/hip_runtime.h>
#include <math.h>

// TopKMoEGate: T = B*S = 16384 tokens, D = 1024, E = 64, K = 2.
// Lane = expert (E == wave width). Wave owns 8 tokens.
// Round-2 change: x is wave-uniform per (g, token) -> read it via the SCALAR
// pipe (s_load) / VMEM instead of LDS broadcasts, which saturated the LDS pipe
// in round 1 (2304 ds_read_b128/wave ~= 92 us model vs 83 us measured).
// LDS now holds only gate_w (lane-private reads, 256 b128/wave).
// FMAs packed as float2 -> v_pk_fma_f32 (2x fp32 rate on gfx950).

#define TPB_TOKENS 32       // tokens per block
#define TPW 8               // tokens per wave
#define BK 128              // k-chunk staged in LDS
#define NG (BK / 4)         // 32 float4 groups per chunk
#define DDIM 1024
#define NEXP 64

typedef float v2f __attribute__((ext_vector_type(2)));

#if defined(__has_builtin)
#if __has_builtin(__builtin_elementwise_fma)
#define HAVE_EW_FMA 1
#endif
#endif

static __device__ __forceinline__ v2f pk_fma(v2f a, v2f b, v2f c) {
#ifdef HAVE_EW_FMA
    return __builtin_elementwise_fma(a, b, c);
#else
    v2f r; r.x = fmaf(a.x, b.x, c.x); r.y = fmaf(a.y, b.y, c.y); return r;
#endif
}

__global__ __launch_bounds__(256, 2)
void moe_gate_kernel(const float* __restrict__ x,
                     const float* __restrict__ gate_w,
                     const float* __restrict__ noise_weight,
                     const float* __restrict__ noise,
                     float* __restrict__ out_w,   // [T][64] fp32
                     float* __restrict__ out_i)   // [T][2] indices as fp32
{
    // w chunk only: unit = g*66 + e (float4 units; stride 66 keeps the
    // compute read at fixed g consecutive across lanes -> conflict-free).
    __shared__ float4 ws4[NG * 66];                 // 33792 B

    const int tid  = threadIdx.x;
    const int lane = tid & 63;                      // expert id
    // Force wave id uniform so x addresses are provably wave-uniform
    // -> scalar (SMEM) loads instead of LDS/VMEM broadcasts.
    const int wv   = __builtin_amdgcn_readfirstlane(tid >> 6);
    const int tokBase = blockIdx.x * TPB_TOKENS;

    v2f acc[TPW][2];
    #pragma unroll
    for (int t = 0; t < TPW; ++t) { acc[t][0] = (v2f)0.f; acc[t][1] = (v2f)0.f; }

    const float nw = noise_weight[lane];

    // staging assignment for gate_w
    const int w_g  = tid & 31;          // k-group
    const int w_e0 = tid >> 5;          // 0..7 (+8r covers 64 experts)

    // wave-uniform base pointer for this wave's 8 token rows
    const float* xw = x + (size_t)(tokBase + wv * TPW) * DDIM;

    for (int c = 0; c < DDIM / BK; ++c) {
        const int k0 = c * BK;
        __syncthreads();
        // stage gate_w chunk: 8 rows/thread, coalesced 512B segments
        #pragma unroll
        for (int r = 0; r < 8; ++r) {
            const int e = w_e0 + 8 * r;
            ws4[w_g * 66 + e] = *(const float4*)&gate_w[e * DDIM + k0 + w_g * 4];
        }
        __syncthreads();
        // compute: per g: 1 private LDS w-read + 8 uniform (scalar) x-reads
        //          + 16 v_pk_fma_f32
        #pragma unroll 4
        for (int g = 0; g < NG; ++g) {
            const float4 w4 = ws4[g * 66 + lane];
            const v2f wlo = {w4.x, w4.y};
            const v2f whi = {w4.z, w4.w};
            #pragma unroll
            for (int t = 0; t < TPW; ++t) {
                const float4 x4 = *(const float4*)&xw[(size_t)t * DDIM + k0 + g * 4];
                const v2f xlo = {x4.x, x4.y};
                const v2f xhi = {x4.z, x4.w};
                acc[t][0] = pk_fma(wlo, xlo, acc[t][0]);
                acc[t][1] = pk_fma(whi, xhi, acc[t][1]);
            }
        }
    }

    // epilogue: noise, top-2, sparse softmax, store
    #pragma unroll
    for (int t = 0; t < TPW; ++t) {
        const int tok = tokBase + wv * TPW + t;
        const float logit = (acc[t][0].x + acc[t][0].y) + (acc[t][1].x + acc[t][1].y);
        const float ln = fmaf(noise[(size_t)tok * NEXP + lane], nw, logit);

        // top-1 (ties -> lower index, matching jax.lax.top_k)
        float v1 = ln; int i1 = lane;
        #pragma unroll
        for (int off = 32; off > 0; off >>= 1) {
            const float vo = __shfl_xor(v1, off, 64);
            const int   io = __shfl_xor(i1, off, 64);
            if (vo > v1 || (vo == v1 && io < i1)) { v1 = vo; i1 = io; }
        }
        // top-2: exclude i1
        float v2 = (lane == i1) ? -3.4e38f : ln; int i2 = lane;
        #pragma unroll
        for (int off = 32; off > 0; off >>= 1) {
            const float vo = __shfl_xor(v2, off, 64);
            const int   io = __shfl_xor(i2, off, 64);
            if (vo > v2 || (vo == v2 && io < i2)) { v2 = vo; i2 = io; }
        }

        const float d   = expf(v2 - v1);       // exp(l2 - l1) <= 1
        const float inv = 1.f / (1.f + d);
        const float wgt = (lane == i1) ? inv : ((lane == i2) ? d * inv : 0.f);
        out_w[(size_t)tok * NEXP + lane] = wgt;
        if (lane == 0) {
            out_i[(size_t)tok * 2]     = (float)i1;
            out_i[(size_t)tok * 2 + 1] = (float)i2;
        }
    }
}

extern "C" void kernel_launch(void* const* d_in, const int* in_sizes, int n_in,
                              void* d_out, int out_size, void* d_ws, size_t ws_size,
                              hipStream_t stream) {
    const float* x     = (const float*)d_in[0];
    const float* gw    = (const float*)d_in[1];
    const float* nwt   = (const float*)d_in[2];
    const float* noise = (const float*)d_in[3];
    const int T = in_sizes[0] / DDIM;                 // 16384 tokens
    float* out_w = (float*)d_out;                     // [T][64]
    float* out_i = (float*)d_out + (size_t)T * NEXP;  // [T][2] as float
    const int blocks = T / TPB_TOKENS;                // 512
    hipLaunchKernelGGL(moe_gate_kernel, dim3(blocks), dim3(256), 0, stream,
                       x, gw, nwt, noise, out_w, out_i);
}

// Round 3
// 144.331 us; speedup vs baseline: 1.2862x; 1.2862x over previous
//
#include <hip/hip_runtime.h>
#include <math.h>

// TopKMoEGate: T = 16384 tokens, D = 1024, E = 64, K(top) = 2.
// Round 3: register-tiled GEMM (8 tok x 8 exp per thread) + split-K=8 +
// separate reduce/top-2 kernel.
//  - x staged in LDS transposed (xT[k][tok]) with group-stride-12 swizzle
//    -> compute reads are 2x ds_read_b128/k/thread at optimal 4 bank phases.
//  - w read DIRECTLY from global (L1/L2-resident 256 KB, broadcast across
//    token-lanes) -> w traffic moved off the LDS pipe (round-1 lesson:
//    uniform LDS reads cost full throughput, ~12cyc/b128, no dedup).
//  - LDS bytes/MAC = 0.5 -> VALU-bound: floor 13.7 us at 157 TF.
//  - split-K partials (fp32) in d_ws, L3-resident; reduce kernel does
//    sum + noise + top-2 butterfly (verified in round 1) + sparse softmax.

#define DDIM 1024
#define NEXP 64
#define NTOK 16384
#define TILE_T 256          // tokens per block (kernel 1)
#define BK 32               // k-chunk staged in LDS
#define XROW 384            // xT row stride in floats (32 groups * 12)

__global__ __launch_bounds__(256, 2)
void gemm_partial_kernel(const float* __restrict__ x,
                         const float* __restrict__ gate_w,
                         float* __restrict__ part,   // [S][NTOK][NEXP]
                         int nsplit, int ksize)      // ksize = DDIM/nsplit
{
    // xT chunk: unit(k,t) = k*XROW + (t>>3)*12 + (t&7)   (4 pad units/group)
    __shared__ float xT[BK * XROW];                  // 49152 B

    const int tid   = threadIdx.x;
    const int tile  = blockIdx.x & 63;               // 64 token tiles
    const int split = blockIdx.x >> 6;
    const int tokBase = tile * TILE_T;
    const int k0 = split * ksize;

    const int tc = tid & 31;                         // token group 0..31
    const int te = tid >> 5;                         // expert group 0..7

    float acc[8][8];
    #pragma unroll
    for (int i = 0; i < 8; ++i)
        #pragma unroll
        for (int r = 0; r < 8; ++r) acc[i][r] = 0.f;

    const int s_tok = tid >> 3;                      // staging: token within pass
    const int s_u   = tid & 7;                       // staging: float4 within row

    for (int kc = 0; kc < ksize; kc += BK) {
        const int kg = k0 + kc;
        __syncthreads();
        // stage x chunk transposed: 8 passes x (1 coalesced float4 read + 4 b32 writes)
        #pragma unroll
        for (int p = 0; p < 8; ++p) {
            const int tok = p * 32 + s_tok;
            const float4 v = *(const float4*)&x[(size_t)(tokBase + tok) * DDIM + kg + s_u * 4];
            const int gbase = (tok >> 3) * 12 + (tok & 7);
            xT[(s_u * 4 + 0) * XROW + gbase] = v.x;
            xT[(s_u * 4 + 1) * XROW + gbase] = v.y;
            xT[(s_u * 4 + 2) * XROW + gbase] = v.z;
            xT[(s_u * 4 + 3) * XROW + gbase] = v.w;
        }
        __syncthreads();

        #pragma unroll 2
        for (int kk = 0; kk < BK / 4; ++kk) {
            // w fragment: 8 expert rows x 4 k, straight from global (L1-hot)
            float4 wf[8];
            #pragma unroll
            for (int r = 0; r < 8; ++r)
                wf[r] = *(const float4*)&gate_w[(size_t)(te * 8 + r) * DDIM + kg + kk * 4];
            #pragma unroll
            for (int j = 0; j < 4; ++j) {
                const float4 xa = *(const float4*)&xT[(kk * 4 + j) * XROW + tc * 12];
                const float4 xb = *(const float4*)&xT[(kk * 4 + j) * XROW + tc * 12 + 4];
                const float xv[8] = {xa.x, xa.y, xa.z, xa.w, xb.x, xb.y, xb.z, xb.w};
                #pragma unroll
                for (int r = 0; r < 8; ++r) {
                    const float wv = ((const float*)&wf[r])[j];
                    #pragma unroll
                    for (int i = 0; i < 8; ++i)
                        acc[i][r] = fmaf(xv[i], wv, acc[i][r]);
                }
            }
        }
    }

    // store partial tile: [split][tok][e]
    #pragma unroll
    for (int i = 0; i < 8; ++i) {
        float* dst = &part[((size_t)split * NTOK + tokBase + tc * 8 + i) * NEXP + te * 8];
        float4 a = {acc[i][0], acc[i][1], acc[i][2], acc[i][3]};
        float4 b = {acc[i][4], acc[i][5], acc[i][6], acc[i][7]};
        *(float4*)dst = a;
        *(float4*)(dst + 4) = b;
    }
}

__global__ __launch_bounds__(256)
void reduce_topk_kernel(const float* __restrict__ part,
                        const float* __restrict__ noise_weight,
                        const float* __restrict__ noise,
                        float* __restrict__ out_w,   // [NTOK][64]
                        float* __restrict__ out_i,   // [NTOK][2] as fp32
                        int nsplit)
{
    const int lane = threadIdx.x & 63;               // expert id
    const int wv   = threadIdx.x >> 6;
    const int token = blockIdx.x * 4 + wv;

    float sum = 0.f;
    for (int s = 0; s < nsplit; ++s)
        sum += part[((size_t)s * NTOK + token) * NEXP + lane];

    const float ln = fmaf(noise[(size_t)token * NEXP + lane], noise_weight[lane], sum);

    // top-1 (ties -> lower index, matching jax.lax.top_k)
    float v1 = ln; int i1 = lane;
    #pragma unroll
    for (int off = 32; off > 0; off >>= 1) {
        const float vo = __shfl_xor(v1, off, 64);
        const int   io = __shfl_xor(i1, off, 64);
        if (vo > v1 || (vo == v1 && io < i1)) { v1 = vo; i1 = io; }
    }
    // top-2: exclude i1
    float v2 = (lane == i1) ? -3.4e38f : ln; int i2 = lane;
    #pragma unroll
    for (int off = 32; off > 0; off >>= 1) {
        const float vo = __shfl_xor(v2, off, 64);
        const int   io = __shfl_xor(i2, off, 64);
        if (vo > v2 || (vo == v2 && io < i2)) { v2 = vo; i2 = io; }
    }

    const float d   = expf(v2 - v1);
    const float inv = 1.f / (1.f + d);
    const float wgt = (lane == i1) ? inv : ((lane == i2) ? d * inv : 0.f);
    out_w[(size_t)token * NEXP + lane] = wgt;
    if (lane == 0) {
        out_i[(size_t)token * 2]     = (float)i1;
        out_i[(size_t)token * 2 + 1] = (float)i2;
    }
}

extern "C" void kernel_launch(void* const* d_in, const int* in_sizes, int n_in,
                              void* d_out, int out_size, void* d_ws, size_t ws_size,
                              hipStream_t stream) {
    const float* x     = (const float*)d_in[0];
    const float* gw    = (const float*)d_in[1];
    const float* nwt   = (const float*)d_in[2];
    const float* noise = (const float*)d_in[3];
    float* out_w = (float*)d_out;                     // [NTOK][64]
    float* out_i = (float*)d_out + (size_t)NTOK * NEXP;  // [NTOK][2] as float
    float* part  = (float*)d_ws;

    // split-K sized to the workspace (partials: S * NTOK * NEXP * 4 bytes)
    int S = 8;
    while (S > 1 && (size_t)S * NTOK * NEXP * 4 > ws_size) S >>= 1;
    const int ksize = DDIM / S;

    hipLaunchKernelGGL(gemm_partial_kernel, dim3(64 * S), dim3(256), 0, stream,
                       x, gw, part, S, ksize);
    hipLaunchKernelGGL(reduce_topk_kernel, dim3(NTOK / 4), dim3(256), 0, stream,
                       part, nwt, noise, out_w, out_i, S);
}